// Round 17
// baseline (145.656 us; speedup 1.0000x reference)
//
#include <hip/hip_runtime.h>
#include <stdint.h>

#define TDIM 4096   // tokens = 2*2048
#define KDIM 4096   // IN_F
#define NDIM 4096   // OUT_F
#define RANK 128
#define NG   32
#define NCHUNK 64   // per-(row, 64-col) partial-max chunks

typedef __attribute__((ext_vector_type(4))) int   i32x4;
typedef __attribute__((ext_vector_type(4))) float f32x4;
typedef __attribute__((ext_vector_type(8))) short short8;
typedef __attribute__((ext_vector_type(8))) unsigned short u16x8;
typedef __attribute__((ext_vector_type(8))) char c8;

__device__ inline unsigned short f2bf(float f) {   // f32 -> bf16 RNE
    union { float f; unsigned u; } v; v.f = f;
    const unsigned r = v.u + 0x7FFF + ((v.u >> 16) & 1);
    return (unsigned short)(r >> 16);
}
__device__ inline float bf2f(unsigned short h) {
    union { unsigned u; float f; } v; v.u = (unsigned)h << 16;
    return v.f;
}

// ---------------------------------------------------------------------------
// Kernel 1 (merged): blocks 0..4095 = per-token activation quant;
// blocks 4096..4479 = svd bf16 conversion. (unchanged)
// ---------------------------------------------------------------------------
__global__ __launch_bounds__(256) void prep_kernel(
    const float* __restrict__ x, int8_t* __restrict__ xq,
    float* __restrict__ scale_x,
    const float* __restrict__ svd_up, const float* __restrict__ svd_down,
    unsigned short* __restrict__ upb, unsigned short* __restrict__ dnt)
{
    if (blockIdx.x < 4096) {
        const int row = blockIdx.x;
        const float4* xr = (const float4*)(x + (size_t)row * KDIM);
        __shared__ float4 buf[1024];
        __shared__ float wred[4];

        float m = 0.f;
        #pragma unroll
        for (int j = 0; j < 4; ++j) {
            const float4 v = xr[threadIdx.x + j * 256];
            buf[threadIdx.x + j * 256] = v;
            m = fmaxf(m, fmaxf(fmaxf(fabsf(v.x), fabsf(v.y)),
                               fmaxf(fabsf(v.z), fabsf(v.w))));
        }
        #pragma unroll
        for (int off = 32; off > 0; off >>= 1)
            m = fmaxf(m, __shfl_xor(m, off, 64));
        if ((threadIdx.x & 63) == 0) wred[threadIdx.x >> 6] = m;
        __syncthreads();
        const float mt = fmaxf(fmaxf(wred[0], wred[1]), fmaxf(wred[2], wred[3]));
        const float sx = mt / 127.0f;
        if (threadIdx.x == 0) scale_x[row] = sx;

        char4* xo = (char4*)(xq + (size_t)row * KDIM);
        #pragma unroll
        for (int j = 0; j < 4; ++j) {
            const float4 v = buf[threadIdx.x + j * 256];
            char4 q;
            q.x = (char)fminf(fmaxf(rintf(v.x / sx), -128.f), 127.f);
            q.y = (char)fminf(fmaxf(rintf(v.y / sx), -128.f), 127.f);
            q.z = (char)fminf(fmaxf(rintf(v.z / sx), -128.f), 127.f);
            q.w = (char)fminf(fmaxf(rintf(v.w / sx), -128.f), 127.f);
            xo[threadIdx.x + j * 256] = q;
        }
    } else {
        const int b = blockIdx.x - 4096;
        if (b < 256) {
            const int t = b * 256 + threadIdx.x;
            const int i  = t >> 4;
            const int k0 = (t & 15) * 8;
            u16x8 v;
            #pragma unroll
            for (int j = 0; j < 8; ++j)
                v[j] = f2bf(svd_down[(size_t)(k0 + j) * KDIM + i]);
            *(u16x8*)(dnt + (size_t)i * RANK + k0) = v;
        } else {
            const int t = (b - 256) * 256 + threadIdx.x;
            const float4* src = (const float4*)svd_up + (size_t)t * 4;
            #pragma unroll
            for (int h = 0; h < 2; ++h) {
                const float4 a = src[h * 2], c = src[h * 2 + 1];
                u16x8 v;
                v[0] = f2bf(a.x); v[1] = f2bf(a.y); v[2] = f2bf(a.z); v[3] = f2bf(a.w);
                v[4] = f2bf(c.x); v[5] = f2bf(c.y); v[6] = f2bf(c.z); v[7] = f2bf(c.w);
                *(u16x8*)(upb + (size_t)t * 16 + h * 8) = v;
            }
        }
    }
}

// ---------------------------------------------------------------------------
// Kernel 2 (R16): W dequant + SVD corr -> bf16 wf (HBM scratch) + partial
// row max. Replaces the 128KB-LDS fused_w monolith (pinned at 1 block/CU,
// 2 waves/SIMD, ~50us vs 13us floor; every in-place fix — more waves (hit
// the 1024-thr 64-VGPR tier), reg prefetch — was null). This is R4's
// VALIDATED w_pass1_mfma structure (grid (64,32), 4 waves 2Mx2N, 64x128
// tile) with three edits:
//  - Wq/scale/zp preloaded to registers BEFORE the MFMA loop (T14: their
//    ~600cyc latency hides under the 32 MFMAs + dnt loads).
//  - writes bf16 (32MB, half of R4's fp32 64MB) via per-wave LDS bounce:
//    MFMA-scattered lanes -> st[32][64] (XOR (row>>2&3)<<4, write-conflict
//    free) -> coalesced 16B-run stores.
//  - row max on bf16 BITS (identical semantics to fused_w -> absmax 0.25).
// 16KB LDS, __launch_bounds__(256,3) -> 3+ blocks/CU, 12 waves/CU.
// ---------------------------------------------------------------------------
__global__ __launch_bounds__(256, 3) void w_pass1_kernel(
    const int* __restrict__ Wq, const float* __restrict__ scale,
    const float* __restrict__ zp,
    const unsigned short* __restrict__ upb,   // [4096][128] bf16
    const unsigned short* __restrict__ dnt,   // [4096][128] bf16 (down^T)
    unsigned short* __restrict__ wfb,         // [4096][4096] bf16 out
    float* __restrict__ partial_max)
{
    __shared__ unsigned short st[4][32][64];   // 16 KB, per-wave staging

    const int lane = threadIdx.x & 63, wid = threadIdx.x >> 6;
    const int wm = wid >> 1, wn = wid & 1;
    const int l15 = lane & 15, l16 = lane >> 4;
    const int row0 = blockIdx.x * 64 + wm * 32;
    const int col0 = blockIdx.y * 128 + wn * 64;
    const int g = blockIdx.y;                  // quant group (128-col)

    // A fragments (validated layout)
    short8 af[2][4];
    #pragma unroll
    for (int mi = 0; mi < 2; ++mi)
        #pragma unroll
        for (int kk = 0; kk < 4; ++kk)
            af[mi][kk] = *(const short8*)(upb +
                (size_t)(row0 + mi * 16 + l15) * RANK + kk * 32 + l16 * 8);

    // early Wq / scale / zp loads (consumed after the MFMAs)
    int   q[2][4][4];
    float s[2][4], z[2][4];
    #pragma unroll
    for (int mi = 0; mi < 2; ++mi)
        #pragma unroll
        for (int j = 0; j < 4; ++j) {
            const int row = row0 + mi * 16 + l16 * 4 + j;
            s[mi][j] = scale[row * NG + g];
            z[mi][j] = zp[row * NG + g];
            #pragma unroll
            for (int ni = 0; ni < 4; ++ni)
                q[mi][ni][j] = Wq[(size_t)row * KDIM + col0 + ni * 16 + l15];
        }

    // correction GEMM (B frags loaded inline)
    f32x4 acc[2][4];
    #pragma unroll
    for (int mi = 0; mi < 2; ++mi)
        #pragma unroll
        for (int ni = 0; ni < 4; ++ni) acc[mi][ni] = (f32x4){0.f, 0.f, 0.f, 0.f};
    #pragma unroll
    for (int kk = 0; kk < 4; ++kk)
        #pragma unroll
        for (int ni = 0; ni < 4; ++ni) {
            const short8 bfr = *(const short8*)(dnt +
                (size_t)(col0 + ni * 16 + l15) * RANK + kk * 32 + l16 * 8);
            #pragma unroll
            for (int mi = 0; mi < 2; ++mi)
                acc[mi][ni] = __builtin_amdgcn_mfma_f32_16x16x32_bf16(
                                  af[mi][kk], bfr, acc[mi][ni], 0, 0, 0);
        }

    // epilogue: wf -> bf16 -> LDS (swizzled), row max on bits
    unsigned umax[2][4];
    #pragma unroll
    for (int mi = 0; mi < 2; ++mi)
        #pragma unroll
        for (int j = 0; j < 4; ++j) umax[mi][j] = 0u;

    #pragma unroll
    for (int mi = 0; mi < 2; ++mi)
        #pragma unroll
        for (int ni = 0; ni < 4; ++ni)
            #pragma unroll
            for (int j = 0; j < 4; ++j) {
                const float wf = ((float)q[mi][ni][j] - z[mi][j]) * s[mi][j]
                                 + acc[mi][ni][j];
                const unsigned short h = f2bf(wf);
                const int r = mi * 16 + l16 * 4 + j;           // 0..31
                const int c = ni * 16 + l15;                   // 0..63
                st[wid][r][c ^ (((r >> 2) & 3) << 4)] = h;
                const unsigned a = h & 0x7FFFu;
                umax[mi][j] = (a > umax[mi][j]) ? a : umax[mi][j];
            }

    // partial row max (16 l15 lanes share a row)
    #pragma unroll
    for (int mi = 0; mi < 2; ++mi)
        #pragma unroll
        for (int j = 0; j < 4; ++j) {
            unsigned v = umax[mi][j];
            v = max(v, (unsigned)__shfl_xor((int)v, 1, 64));
            v = max(v, (unsigned)__shfl_xor((int)v, 2, 64));
            v = max(v, (unsigned)__shfl_xor((int)v, 4, 64));
            v = max(v, (unsigned)__shfl_xor((int)v, 8, 64));
            if (l15 == 0) {
                const int row = row0 + mi * 16 + l16 * 4 + j;
                partial_max[(size_t)row * NCHUNK + blockIdx.y * 2 + wn] =
                    bf2f((unsigned short)v);
            }
        }

    // wave-local readback (same-wave LDS dependency; no block barrier) ->
    // coalesced global stores: lane covers 64B run of one row.
    const int rr = lane >> 1, half = lane & 1;
    const int gro = row0 + rr;                 // absolute row (row0 incl wm)
    #pragma unroll
    for (int k = 0; k < 4; ++k) {
        const int c0 = half * 32 + k * 8;
        const u16x8 v = *(const u16x8*)&st[wid][rr][c0 ^ (((rr >> 2) & 3) << 4)];
        *(u16x8*)(wfb + (size_t)gro * KDIM + col0 + c0) = v;
    }
}

// ---------------------------------------------------------------------------
// Kernel 2b: reduce 64 per-chunk partial maxes -> scale_w (R4's, validated).
// ---------------------------------------------------------------------------
__global__ __launch_bounds__(256) void finalize_sw_kernel(
    const float* __restrict__ partial_max, float* __restrict__ scale_w)
{
    const int o = blockIdx.x * 256 + threadIdx.x;
    const float4* p = (const float4*)(partial_max + (size_t)o * NCHUNK);
    float m = 0.f;
    #pragma unroll
    for (int i = 0; i < NCHUNK / 4; ++i) {
        const float4 v = p[i];
        m = fmaxf(m, fmaxf(fmaxf(v.x, v.y), fmaxf(v.z, v.w)));
    }
    scale_w[o] = m / 127.0f;
}

// ---------------------------------------------------------------------------
// Kernel 3 (R16): quantize bf16 wf -> int8 wq. Pure streaming: block = 4
// rows x 4096 cols (grid 1024), wave = one row, 1KB/inst loads, 512B/inst
// stores, fully coalesced. Same math as fused_w pass 2 (true division).
// ---------------------------------------------------------------------------
__global__ __launch_bounds__(256) void w_quant_kernel(
    const unsigned short* __restrict__ wfb, const float* __restrict__ scale_w,
    int8_t* __restrict__ wq)
{
    const int row = blockIdx.x * 4 + (threadIdx.x >> 6);
    const int lane = threadIdx.x & 63;
    const float sw = scale_w[row];
    const unsigned short* src = wfb + (size_t)row * KDIM;
    int8_t* dst = wq + (size_t)row * KDIM;
    #pragma unroll
    for (int k = 0; k < 8; ++k) {
        const int c0 = k * 512 + lane * 8;
        const u16x8 h = *(const u16x8*)(src + c0);
        c8 qv;
        #pragma unroll
        for (int e = 0; e < 8; ++e) {
            const float f = bf2f((unsigned short)h[e]);
            qv[e] = (char)fminf(fmaxf(rintf(f / sw), -128.f), 127.f);
        }
        *(c8*)(dst + c0) = qv;
    }
}

// ---------------------------------------------------------------------------
// Kernel 4: int8 GEMM 256x256, BK=64, 4-deep rotation (FROZEN from R10).
// Five schedule variants (R5-R10) all plateau at ~2700 cyc/tile = LDS-pipe
// + MFMA-pipe serialized (the m97-ceiling phenomenon). MfmaUtil ~40%.
// ---------------------------------------------------------------------------
__global__ __launch_bounds__(512, 2) void gemm_i8_kernel(
    const int8_t* __restrict__ Aq,   // [T][K]
    const int8_t* __restrict__ Bq,   // [N][K]
    const float* __restrict__ scale_x, const float* __restrict__ scale_w,
    const float* __restrict__ bias, float* __restrict__ out)
{
    __shared__ __align__(16) int8_t lds[131072];
    // A: buf*16384, bufs 0..3 in [0,64K); B: 65536 + buf*16384 in [64K,128K)

    const int tid  = threadIdx.x;
    const int lane = tid & 63;
    const int wid  = tid >> 6;
    const int wmp  = wid >> 2;
    const int wnp  = wid & 3;
    const int l15  = lane & 15, l16 = lane >> 4;

    const int swz  = (blockIdx.x & 7) * 32 + (blockIdx.x >> 3);
    const int row0 = (swz >> 4) * 256;
    const int col0 = (swz & 15) * 256;

    const int srow = wid * 16 + (lane >> 2);
    const int scol = ((lane & 3) ^ ((lane >> 3) & 3)) * 16;
    const int8_t* const A0g = Aq + (size_t)(row0 + srow) * KDIM + scol;
    const int8_t* const B0g = Bq + (size_t)(col0 + srow) * KDIM + scol;
    int8_t* const ldsw = lds + wid * 1024;

#define STAGE_A(db, h, kt) \
    __builtin_amdgcn_global_load_lds( \
        (const __attribute__((address_space(1))) void*)(A0g + (size_t)(h) * 128 * KDIM + (kt) * 64), \
        (__attribute__((address_space(3))) void*)(ldsw + (db) * 16384 + (h) * 8192), 16, 0, 0)
#define STAGE_B(db, h, kt) \
    __builtin_amdgcn_global_load_lds( \
        (const __attribute__((address_space(1))) void*)(B0g + (size_t)(h) * 128 * KDIM + (kt) * 64), \
        (__attribute__((address_space(3))) void*)(ldsw + 65536 + (db) * 16384 + (h) * 8192), 16, 0, 0)

    const int rslot = (l16 ^ ((lane >> 1) & 3)) * 16;
    const int aoff = wmp * 8192 + l15 * 64 + rslot;
    const int boff = (wnp >> 1) * 8192 + (wnp & 1) * 4096 + l15 * 64 + rslot;

    i32x4 A0a[4], Ba[4], A0b[4], Bb[4], Ar1[4];
    i32x4 acc[8][4];
    #pragma unroll
    for (int m = 0; m < 8; ++m)
        #pragma unroll
        for (int n = 0; n < 4; ++n) acc[m][n] = (i32x4){0, 0, 0, 0};

#define LDA_Q(db, qm, R) { const int8_t* p = lds + (db) * 16384 + aoff + (qm) * 4096; \
    R[0] = *(const i32x4*)(p);        R[1] = *(const i32x4*)(p + 1024); \
    R[2] = *(const i32x4*)(p + 2048); R[3] = *(const i32x4*)(p + 3072); }
#define LDB_ALL(db, R) { const int8_t* p = lds + 65536 + (db) * 16384 + boff; \
    R[0] = *(const i32x4*)(p);        R[1] = *(const i32x4*)(p + 1024); \
    R[2] = *(const i32x4*)(p + 2048); R[3] = *(const i32x4*)(p + 3072); }
#define MR(i, AR, ai, BR) { \
    acc[i][0] = __builtin_amdgcn_mfma_i32_16x16x64_i8(AR[ai], BR[0], acc[i][0], 0, 0, 0); \
    acc[i][1] = __builtin_amdgcn_mfma_i32_16x16x64_i8(AR[ai], BR[1], acc[i][1], 0, 0, 0); \
    acc[i][2] = __builtin_amdgcn_mfma_i32_16x16x64_i8(AR[ai], BR[2], acc[i][2], 0, 0, 0); \
    acc[i][3] = __builtin_amdgcn_mfma_i32_16x16x64_i8(AR[ai], BR[3], acc[i][3], 0, 0, 0); }

#define BAR   __builtin_amdgcn_s_barrier()
#define VMCNT4 asm volatile("s_waitcnt vmcnt(4)" ::: "memory")
#define VMCNT8 asm volatile("s_waitcnt vmcnt(8)" ::: "memory")
#define VMCNT0 asm volatile("s_waitcnt vmcnt(0)" ::: "memory")
#define PRIO1 __builtin_amdgcn_s_setprio(1)
#define PRIO0 __builtin_amdgcn_s_setprio(0)
#define SGB(m, n) __builtin_amdgcn_sched_group_barrier(m, n, 0)
#define SGB_PIN { SGB(0x20, 4); SGB(0x100, 4); SGB(0x8, 8); \
                  SGB(0x100, 4); SGB(0x8, 8); SGB(0x100, 4); SGB(0x8, 16); }

#define INTERVAL(rb, sb, u, CA0, CB, NA0, NB, nb) { \
    VMCNT4; BAR; \
    STAGE_A(sb, 0, u); STAGE_A(sb, 1, u); STAGE_B(sb, 0, u); STAGE_B(sb, 1, u); \
    LDA_Q(rb, 1, Ar1); \
    PRIO1; MR(0, CA0, 0, CB); MR(1, CA0, 1, CB); PRIO0; \
    LDB_ALL(nb, NB); \
    PRIO1; MR(2, CA0, 2, CB); MR(3, CA0, 3, CB); PRIO0; \
    LDA_Q(nb, 0, NA0); \
    PRIO1; MR(4, Ar1, 0, CB); MR(5, Ar1, 1, CB); \
           MR(6, Ar1, 2, CB); MR(7, Ar1, 3, CB); PRIO0; \
    SGB_PIN; }

    STAGE_A(0, 0, 0); STAGE_A(0, 1, 0); STAGE_B(0, 0, 0); STAGE_B(0, 1, 0);
    STAGE_A(1, 0, 1); STAGE_A(1, 1, 1); STAGE_B(1, 0, 1); STAGE_B(1, 1, 1);
    STAGE_A(2, 0, 2); STAGE_A(2, 1, 2); STAGE_B(2, 0, 2); STAGE_B(2, 1, 2);
    VMCNT8;
    BAR;
    LDB_ALL(0, Ba); LDA_Q(0, 0, A0a);

    for (int k = 0; k < 16; ++k) {        // 4 tiles per iteration
        const int t0 = 4 * k;
        const int u0 = (t0 + 3 > 63) ? 63 : t0 + 3;
        const int u1 = (t0 + 4 > 63) ? 63 : t0 + 4;
        const int u2 = (t0 + 5 > 63) ? 63 : t0 + 5;
        const int u3 = (t0 + 6 > 63) ? 63 : t0 + 6;
        INTERVAL(0, 3, u0, A0a, Ba, A0b, Bb, 1);
        INTERVAL(1, 0, u1, A0b, Bb, A0a, Ba, 2);
        INTERVAL(2, 1, u2, A0a, Ba, A0b, Bb, 3);
        INTERVAL(3, 2, u3, A0b, Bb, A0a, Ba, 0);
    }
    VMCNT0;

    const int orow0 = row0 + wmp * 128;
    const int ocol0 = col0 + wnp * 64;
    #pragma unroll
    for (int fn = 0; fn < 4; ++fn) {
        const int col = ocol0 + fn * 16 + l15;
        const float sw = scale_w[col];
        const float bv = bias[col];
        #pragma unroll
        for (int fm = 0; fm < 8; ++fm) {
            #pragma unroll
            for (int j = 0; j < 4; ++j) {
                const int row = orow0 + fm * 16 + l16 * 4 + j;
                out[(size_t)row * NDIM + col] =
                    (float)acc[fm][fn][j] * scale_x[row] * sw + bv;
            }
        }
    }
#undef STAGE_A
#undef STAGE_B
#undef LDA_Q
#undef LDB_ALL
#undef MR
#undef INTERVAL
#undef SGB
#undef SGB_PIN
#undef BAR
#undef VMCNT4
#undef VMCNT8
#undef VMCNT0
#undef PRIO1
#undef PRIO0
}

// ---------------------------------------------------------------------------
extern "C" void kernel_launch(void* const* d_in, const int* in_sizes, int n_in,
                              void* d_out, int out_size, void* d_ws, size_t ws_size,
                              hipStream_t stream)
{
    const float* x        = (const float*)d_in[0];
    const int*   Wq       = (const int*)d_in[1];
    const float* scale    = (const float*)d_in[2];
    const float* zp       = (const float*)d_in[3];
    const float* svd_up   = (const float*)d_in[4];
    const float* svd_down = (const float*)d_in[5];
    const float* bias     = (const float*)d_in[6];
    float* out = (float*)d_out;

    // ws: xq 16MB | wq 16MB | scale_x 16KB | scale_w 16KB | upb 1MB |
    //     dnt 1MB | partial 1MB
    int8_t* xq = (int8_t*)d_ws;
    int8_t* wq = (int8_t*)d_ws + ((size_t)16 << 20);
    float* scale_x = (float*)((char*)d_ws + ((size_t)32 << 20));
    float* scale_w = scale_x + TDIM;
    unsigned short* upb = (unsigned short*)(scale_w + NDIM);
    unsigned short* dnt = upb + (size_t)NDIM * RANK;
    float* partial_max = (float*)(dnt + (size_t)KDIM * RANK);

    // d_out doubles as bf16 wf scratch (32MB of the 64MB buffer) — written
    // by w_pass1, read by w_quant, then fully overwritten by the GEMM.
    unsigned short* wfb = (unsigned short*)d_out;

    prep_kernel<<<4096 + 384, 256, 0, stream>>>(x, xq, scale_x,
                                                svd_up, svd_down, upb, dnt);
    w_pass1_kernel<<<dim3(NDIM / 64, KDIM / 128), 256, 0, stream>>>(
        Wq, scale, zp, upb, dnt, wfb, partial_max);
    finalize_sw_kernel<<<NDIM / 256, 256, 0, stream>>>(partial_max, scale_w);
    w_quant_kernel<<<NDIM / 4, 256, 0, stream>>>(wfb, scale_w, wq);
    gemm_i8_kernel<<<(TDIM / 256) * (NDIM / 256), 512, 0, stream>>>(
        xq, wq, scale_x, scale_w, bias, out);
}

// Round 18
// 131.642 us; speedup vs baseline: 1.1065x; 1.1065x over previous
//
#include <hip/hip_runtime.h>
#include <stdint.h>

#define TDIM 4096   // tokens = 2*2048
#define KDIM 4096   // IN_F
#define NDIM 4096   // OUT_F
#define RANK 128
#define NG   32

typedef __attribute__((ext_vector_type(4))) int   i32x4;
typedef __attribute__((ext_vector_type(4))) float f32x4;
typedef __attribute__((ext_vector_type(8))) short short8;
typedef __attribute__((ext_vector_type(8))) unsigned short u16x8;
typedef __attribute__((ext_vector_type(8))) char c8;

__device__ inline unsigned short f2bf(float f) {   // f32 -> bf16 RNE
    union { float f; unsigned u; } v; v.f = f;
    const unsigned r = v.u + 0x7FFF + ((v.u >> 16) & 1);
    return (unsigned short)(r >> 16);
}
__device__ inline float bf2f(unsigned short h) {
    union { unsigned u; float f; } v; v.u = (unsigned)h << 16;
    return v.f;
}

// ---------------------------------------------------------------------------
// Kernel 1 (merged prep) — R17: conv-down rewritten as an LDS-tiled
// transpose. The old code read svd_down[(k0+j)*KDIM + i] per thread: 8
// dwords at 16KB stride each = 512K scattered 64B-line fetches for 2MB of
// data (est. 8-15us hidden inside prep since R3 — never profiled because
// gemm monopolizes top-5). Now: 128 blocks each transpose a 128k x 32i
// tile through padded LDS [128][33]; reads are 128B runs, writes 256B runs.
// Identical values through identical f2bf -> dnt bit-identical.
//   blocks 0..4095   : per-token activation quant (unchanged)
//   blocks 4096..4223: svd_down transpose -> dnt bf16 [4096][128]
//   blocks 4224..4351: svd_up convert      -> upb bf16 [4096][128]
// ---------------------------------------------------------------------------
__global__ __launch_bounds__(256) void prep_kernel(
    const float* __restrict__ x, int8_t* __restrict__ xq,
    float* __restrict__ scale_x,
    const float* __restrict__ svd_up, const float* __restrict__ svd_down,
    unsigned short* __restrict__ upb, unsigned short* __restrict__ dnt)
{
    __shared__ __align__(16) char shm[128 * 33 * 4 + 64];   // ~16.9 KB union

    if (blockIdx.x < 4096) {
        const int row = blockIdx.x;
        const float4* xr = (const float4*)(x + (size_t)row * KDIM);
        float4* buf = (float4*)shm;                  // 16 KB
        float* wred = (float*)(shm + 16384);

        float m = 0.f;
        #pragma unroll
        for (int j = 0; j < 4; ++j) {
            const float4 v = xr[threadIdx.x + j * 256];
            buf[threadIdx.x + j * 256] = v;
            m = fmaxf(m, fmaxf(fmaxf(fabsf(v.x), fabsf(v.y)),
                               fmaxf(fabsf(v.z), fabsf(v.w))));
        }
        #pragma unroll
        for (int off = 32; off > 0; off >>= 1)
            m = fmaxf(m, __shfl_xor(m, off, 64));
        if ((threadIdx.x & 63) == 0) wred[threadIdx.x >> 6] = m;
        __syncthreads();
        const float mt = fmaxf(fmaxf(wred[0], wred[1]), fmaxf(wred[2], wred[3]));
        const float sx = mt / 127.0f;
        if (threadIdx.x == 0) scale_x[row] = sx;

        char4* xo = (char4*)(xq + (size_t)row * KDIM);
        #pragma unroll
        for (int j = 0; j < 4; ++j) {
            const float4 v = buf[threadIdx.x + j * 256];
            char4 q;
            q.x = (char)fminf(fmaxf(rintf(v.x / sx), -128.f), 127.f);
            q.y = (char)fminf(fmaxf(rintf(v.y / sx), -128.f), 127.f);
            q.z = (char)fminf(fmaxf(rintf(v.z / sx), -128.f), 127.f);
            q.w = (char)fminf(fmaxf(rintf(v.w / sx), -128.f), 127.f);
            xo[threadIdx.x + j * 256] = q;
        }
    } else if (blockIdx.x < 4224) {
        // svd_down [128][4096] -> dnt [4096][128], LDS-tiled transpose
        float (*tl)[33] = (float(*)[33])shm;         // [128][33], padded
        const int i0 = (blockIdx.x - 4096) * 32;
        const int tid = threadIdx.x;

        #pragma unroll
        for (int j = 0; j < 16; ++j) {               // 128k x 32i coalesced
            const int e = j * 256 + tid;
            const int k = e >> 5, il = e & 31;
            tl[k][il] = svd_down[(size_t)k * KDIM + i0 + il];
        }
        __syncthreads();

        #pragma unroll
        for (int r = 0; r < 2; ++r) {                // 16 i-rows per round
            const int il = (tid >> 4) + r * 16;
            const int k0 = (tid & 15) * 8;
            u16x8 v;
            #pragma unroll
            for (int j = 0; j < 8; ++j) v[j] = f2bf(tl[k0 + j][il]);
            *(u16x8*)(dnt + (size_t)(i0 + il) * RANK + k0) = v;
        }
    } else {
        // svd_up [4096][128] -> upb bf16 (straight convert, coalesced)
        const int t = (blockIdx.x - 4224) * 256 + threadIdx.x;
        const float4* src = (const float4*)svd_up + (size_t)t * 4;
        #pragma unroll
        for (int h = 0; h < 2; ++h) {
            const float4 a = src[h * 2], c = src[h * 2 + 1];
            u16x8 v;
            v[0] = f2bf(a.x); v[1] = f2bf(a.y); v[2] = f2bf(a.z); v[3] = f2bf(a.w);
            v[4] = f2bf(c.x); v[5] = f2bf(c.y); v[6] = f2bf(c.z); v[7] = f2bf(c.w);
            *(u16x8*)(upb + (size_t)t * 16 + h * 8) = v;
        }
    }
}

// ---------------------------------------------------------------------------
// Kernel 2 (FUSED, reverted to R10 verbatim — best measured config):
// dequant + SVD corr + row max + quantize. bf16 wf staged in 128KB LDS.
// ---------------------------------------------------------------------------
__global__ __launch_bounds__(512) void fused_w_kernel(
    const int* __restrict__ Wq, const float* __restrict__ scale,
    const float* __restrict__ zp,
    const unsigned short* __restrict__ upb,   // [4096][128] bf16
    const unsigned short* __restrict__ dnt,   // [4096][128] bf16 (down^T)
    int8_t* __restrict__ wq, float* __restrict__ scale_w)
{
    __shared__ unsigned short wfls[16 * 4096];   // 128 KB
    __shared__ float red[16][8];
    __shared__ float swls[16];

    const int tid  = threadIdx.x;
    const int lane = tid & 63, wid = tid >> 6;   // 8 waves
    const int l15  = lane & 15, l16 = lane >> 4;
    const int o0   = blockIdx.x * 16;

    short8 af[4];
    #pragma unroll
    for (int kk = 0; kk < 4; ++kk)
        af[kk] = *(const short8*)(upb + (size_t)(o0 + l15) * RANK + kk * 32 + l16 * 8);

    const int swz = l16 << 4;
    unsigned umax[4] = {0u, 0u, 0u, 0u};

    for (int c = 0; c < 4; ++c) {
        const int cb = wid * 512 + c * 128;
        const int g  = cb >> 7;

        f32x4 acc[8];
        #pragma unroll
        for (int t = 0; t < 8; ++t) acc[t] = (f32x4){0.f, 0.f, 0.f, 0.f};
        #pragma unroll
        for (int t = 0; t < 8; ++t)
            #pragma unroll
            for (int kk = 0; kk < 4; ++kk) {
                const short8 bfr = *(const short8*)(dnt +
                    (size_t)(cb + t * 16 + l15) * RANK + kk * 32 + l16 * 8);
                acc[t] = __builtin_amdgcn_mfma_f32_16x16x32_bf16(
                             af[kk], bfr, acc[t], 0, 0, 0);
            }

        float s[4], z[4];
        #pragma unroll
        for (int j = 0; j < 4; ++j) {
            const int row = o0 + l16 * 4 + j;
            s[j] = scale[row * NG + g];
            z[j] = zp[row * NG + g];
        }

        #pragma unroll
        for (int t = 0; t < 8; ++t) {
            const int col = cb + t * 16 + l15;
            #pragma unroll
            for (int j = 0; j < 4; ++j) {
                const int r = l16 * 4 + j;
                const float q  = (float)Wq[(size_t)(o0 + r) * KDIM + col];
                const float wf = (q - z[j]) * s[j] + acc[t][j];
                const unsigned short h = f2bf(wf);
                wfls[r * 4096 + (col ^ swz)] = h;
                const unsigned a = h & 0x7FFFu;
                umax[j] = (a > umax[j]) ? a : umax[j];
            }
        }
    }

    #pragma unroll
    for (int j = 0; j < 4; ++j) {
        unsigned v = umax[j];
        v = max(v, (unsigned)__shfl_xor((int)v, 1, 64));
        v = max(v, (unsigned)__shfl_xor((int)v, 2, 64));
        v = max(v, (unsigned)__shfl_xor((int)v, 4, 64));
        v = max(v, (unsigned)__shfl_xor((int)v, 8, 64));
        if (l15 == 0) red[l16 * 4 + j][wid] = bf2f((unsigned short)v);
    }
    __syncthreads();
    if (tid < 16) {
        float m = 0.f;
        #pragma unroll
        for (int w = 0; w < 8; ++w) m = fmaxf(m, red[tid][w]);
        const float sw = m / 127.0f;
        swls[tid] = sw;
        scale_w[o0 + tid] = sw;
    }
    __syncthreads();

    const int r  = tid >> 5;
    const int ml = tid & 31;
    const float sw = swls[r];
    const int rsw = ((r >> 2) & 3) << 4;
    int8_t* wrow = wq + (size_t)(o0 + r) * KDIM;
    #pragma unroll
    for (int k = 0; k < 16; ++k) {
        const int c0 = k * 256 + ml * 8;
        const u16x8 h = *(const u16x8*)(wfls + r * 4096 + (c0 ^ rsw));
        c8 qv;
        #pragma unroll
        for (int e = 0; e < 8; ++e) {
            float f = bf2f((unsigned short)h[e]);
            qv[e] = (char)fminf(fmaxf(rintf(f / sw), -128.f), 127.f);
        }
        *(c8*)(wrow + c0) = qv;
    }
}

// ---------------------------------------------------------------------------
// Kernel 4: int8 GEMM 256x256, BK=64, 4-deep rotation (FROZEN from R10).
// Five schedule variants (R5-R10) all plateau at ~2700 cyc/tile = LDS-pipe
// + MFMA-pipe serialized (the m97-ceiling phenomenon). MfmaUtil ~40%.
// ---------------------------------------------------------------------------
__global__ __launch_bounds__(512, 2) void gemm_i8_kernel(
    const int8_t* __restrict__ Aq,   // [T][K]
    const int8_t* __restrict__ Bq,   // [N][K]
    const float* __restrict__ scale_x, const float* __restrict__ scale_w,
    const float* __restrict__ bias, float* __restrict__ out)
{
    __shared__ __align__(16) int8_t lds[131072];
    // A: buf*16384, bufs 0..3 in [0,64K); B: 65536 + buf*16384 in [64K,128K)

    const int tid  = threadIdx.x;
    const int lane = tid & 63;
    const int wid  = tid >> 6;
    const int wmp  = wid >> 2;
    const int wnp  = wid & 3;
    const int l15  = lane & 15, l16 = lane >> 4;

    const int swz  = (blockIdx.x & 7) * 32 + (blockIdx.x >> 3);
    const int row0 = (swz >> 4) * 256;
    const int col0 = (swz & 15) * 256;

    const int srow = wid * 16 + (lane >> 2);
    const int scol = ((lane & 3) ^ ((lane >> 3) & 3)) * 16;
    const int8_t* const A0g = Aq + (size_t)(row0 + srow) * KDIM + scol;
    const int8_t* const B0g = Bq + (size_t)(col0 + srow) * KDIM + scol;
    int8_t* const ldsw = lds + wid * 1024;

#define STAGE_A(db, h, kt) \
    __builtin_amdgcn_global_load_lds( \
        (const __attribute__((address_space(1))) void*)(A0g + (size_t)(h) * 128 * KDIM + (kt) * 64), \
        (__attribute__((address_space(3))) void*)(ldsw + (db) * 16384 + (h) * 8192), 16, 0, 0)
#define STAGE_B(db, h, kt) \
    __builtin_amdgcn_global_load_lds( \
        (const __attribute__((address_space(1))) void*)(B0g + (size_t)(h) * 128 * KDIM + (kt) * 64), \
        (__attribute__((address_space(3))) void*)(ldsw + 65536 + (db) * 16384 + (h) * 8192), 16, 0, 0)

    const int rslot = (l16 ^ ((lane >> 1) & 3)) * 16;
    const int aoff = wmp * 8192 + l15 * 64 + rslot;
    const int boff = (wnp >> 1) * 8192 + (wnp & 1) * 4096 + l15 * 64 + rslot;

    i32x4 A0a[4], Ba[4], A0b[4], Bb[4], Ar1[4];
    i32x4 acc[8][4];
    #pragma unroll
    for (int m = 0; m < 8; ++m)
        #pragma unroll
        for (int n = 0; n < 4; ++n) acc[m][n] = (i32x4){0, 0, 0, 0};

#define LDA_Q(db, qm, R) { const int8_t* p = lds + (db) * 16384 + aoff + (qm) * 4096; \
    R[0] = *(const i32x4*)(p);        R[1] = *(const i32x4*)(p + 1024); \
    R[2] = *(const i32x4*)(p + 2048); R[3] = *(const i32x4*)(p + 3072); }
#define LDB_ALL(db, R) { const int8_t* p = lds + 65536 + (db) * 16384 + boff; \
    R[0] = *(const i32x4*)(p);        R[1] = *(const i32x4*)(p + 1024); \
    R[2] = *(const i32x4*)(p + 2048); R[3] = *(const i32x4*)(p + 3072); }
#define MR(i, AR, ai, BR) { \
    acc[i][0] = __builtin_amdgcn_mfma_i32_16x16x64_i8(AR[ai], BR[0], acc[i][0], 0, 0, 0); \
    acc[i][1] = __builtin_amdgcn_mfma_i32_16x16x64_i8(AR[ai], BR[1], acc[i][1], 0, 0, 0); \
    acc[i][2] = __builtin_amdgcn_mfma_i32_16x16x64_i8(AR[ai], BR[2], acc[i][2], 0, 0, 0); \
    acc[i][3] = __builtin_amdgcn_mfma_i32_16x16x64_i8(AR[ai], BR[3], acc[i][3], 0, 0, 0); }

#define BAR   __builtin_amdgcn_s_barrier()
#define VMCNT4 asm volatile("s_waitcnt vmcnt(4)" ::: "memory")
#define VMCNT8 asm volatile("s_waitcnt vmcnt(8)" ::: "memory")
#define VMCNT0 asm volatile("s_waitcnt vmcnt(0)" ::: "memory")
#define PRIO1 __builtin_amdgcn_s_setprio(1)
#define PRIO0 __builtin_amdgcn_s_setprio(0)
#define SGB(m, n) __builtin_amdgcn_sched_group_barrier(m, n, 0)
#define SGB_PIN { SGB(0x20, 4); SGB(0x100, 4); SGB(0x8, 8); \
                  SGB(0x100, 4); SGB(0x8, 8); SGB(0x100, 4); SGB(0x8, 16); }

#define INTERVAL(rb, sb, u, CA0, CB, NA0, NB, nb) { \
    VMCNT4; BAR; \
    STAGE_A(sb, 0, u); STAGE_A(sb, 1, u); STAGE_B(sb, 0, u); STAGE_B(sb, 1, u); \
    LDA_Q(rb, 1, Ar1); \
    PRIO1; MR(0, CA0, 0, CB); MR(1, CA0, 1, CB); PRIO0; \
    LDB_ALL(nb, NB); \
    PRIO1; MR(2, CA0, 2, CB); MR(3, CA0, 3, CB); PRIO0; \
    LDA_Q(nb, 0, NA0); \
    PRIO1; MR(4, Ar1, 0, CB); MR(5, Ar1, 1, CB); \
           MR(6, Ar1, 2, CB); MR(7, Ar1, 3, CB); PRIO0; \
    SGB_PIN; }

    STAGE_A(0, 0, 0); STAGE_A(0, 1, 0); STAGE_B(0, 0, 0); STAGE_B(0, 1, 0);
    STAGE_A(1, 0, 1); STAGE_A(1, 1, 1); STAGE_B(1, 0, 1); STAGE_B(1, 1, 1);
    STAGE_A(2, 0, 2); STAGE_A(2, 1, 2); STAGE_B(2, 0, 2); STAGE_B(2, 1, 2);
    VMCNT8;
    BAR;
    LDB_ALL(0, Ba); LDA_Q(0, 0, A0a);

    for (int k = 0; k < 16; ++k) {        // 4 tiles per iteration
        const int t0 = 4 * k;
        const int u0 = (t0 + 3 > 63) ? 63 : t0 + 3;
        const int u1 = (t0 + 4 > 63) ? 63 : t0 + 4;
        const int u2 = (t0 + 5 > 63) ? 63 : t0 + 5;
        const int u3 = (t0 + 6 > 63) ? 63 : t0 + 6;
        INTERVAL(0, 3, u0, A0a, Ba, A0b, Bb, 1);
        INTERVAL(1, 0, u1, A0b, Bb, A0a, Ba, 2);
        INTERVAL(2, 1, u2, A0a, Ba, A0b, Bb, 3);
        INTERVAL(3, 2, u3, A0b, Bb, A0a, Ba, 0);
    }
    VMCNT0;

    const int orow0 = row0 + wmp * 128;
    const int ocol0 = col0 + wnp * 64;
    #pragma unroll
    for (int fn = 0; fn < 4; ++fn) {
        const int col = ocol0 + fn * 16 + l15;
        const float sw = scale_w[col];
        const float bv = bias[col];
        #pragma unroll
        for (int fm = 0; fm < 8; ++fm) {
            #pragma unroll
            for (int j = 0; j < 4; ++j) {
                const int row = orow0 + fm * 16 + l16 * 4 + j;
                out[(size_t)row * NDIM + col] =
                    (float)acc[fm][fn][j] * scale_x[row] * sw + bv;
            }
        }
    }
#undef STAGE_A
#undef STAGE_B
#undef LDA_Q
#undef LDB_ALL
#undef MR
#undef INTERVAL
#undef SGB
#undef SGB_PIN
#undef BAR
#undef VMCNT4
#undef VMCNT8
#undef VMCNT0
#undef PRIO1
#undef PRIO0
}

// ---------------------------------------------------------------------------
extern "C" void kernel_launch(void* const* d_in, const int* in_sizes, int n_in,
                              void* d_out, int out_size, void* d_ws, size_t ws_size,
                              hipStream_t stream)
{
    const float* x        = (const float*)d_in[0];
    const int*   Wq       = (const int*)d_in[1];
    const float* scale    = (const float*)d_in[2];
    const float* zp       = (const float*)d_in[3];
    const float* svd_up   = (const float*)d_in[4];
    const float* svd_down = (const float*)d_in[5];
    const float* bias     = (const float*)d_in[6];
    float* out = (float*)d_out;

    // ws: xq 16MB | wq 16MB | scale_x 16KB | scale_w 16KB | upb 1MB | dnt 1MB
    int8_t* xq = (int8_t*)d_ws;
    int8_t* wq = (int8_t*)d_ws + ((size_t)16 << 20);
    float* scale_x = (float*)((char*)d_ws + ((size_t)32 << 20));
    float* scale_w = scale_x + TDIM;
    unsigned short* upb = (unsigned short*)(scale_w + NDIM);
    unsigned short* dnt = upb + (size_t)NDIM * RANK;

    prep_kernel<<<4096 + 128 + 128, 256, 0, stream>>>(x, xq, scale_x,
                                                      svd_up, svd_down, upb, dnt);
    fused_w_kernel<<<NDIM / 16, 512, 0, stream>>>(Wq, scale, zp, upb, dnt,
                                                  wq, scale_w);
    gemm_i8_kernel<<<(TDIM / 256) * (NDIM / 256), 512, 0, stream>>>(
        xq, wq, scale_x, scale_w, bias, out);
}